// Round 8
// baseline (248.681 us; speedup 1.0000x reference)
//
#include <hip/hip_runtime.h>

#define NN 4096
#define NE 32768
#define PED 16
#define HID 128
#define CW 16          // columns per block slice
#define NCHUNK 64      // NN/64 rows per chunk
#define THREADS 1024   // 16 waves
#define PASSES 4       // NCHUNK / 16 waves

typedef _Float16 h_t;
typedef _Float16 h8 __attribute__((ext_vector_type(8)));
typedef unsigned long long u64;

// LDS BYTE offset for SORTED slot p (row rowperm[p]).
// 128-B window = 4 slots x 32 B (lo half 16 B + hi half 16 B = 16 fp16 cols).
// granule g = ((p&3)<<1) | window-parity; hi half = ^16.
__device__ __forceinline__ int xp(int p) {
  int g = ((p & 3) << 1) | ((p >> 2) & 1);
  return ((p >> 2) << 7) | (g << 4);
}

// ---- preprocessing (tiny, one-time) ----

__global__ void count_kernel(const int* __restrict__ senders,
                             const int* __restrict__ receivers,
                             int* __restrict__ outdeg, int* __restrict__ indeg) {
  int e = blockIdx.x * blockDim.x + threadIdx.x;
  if (e < NE) {
    atomicAdd(&outdeg[senders[e]], 1);
    atomicAdd(&indeg[receivers[e]], 1);
  }
}

// counting-sort rows by (clamped) in-degree; per-chunk padded length (even),
// ELL offsets, dinv
__global__ void sort_kernel(const int* __restrict__ indeg, const int* __restrict__ outdeg,
                            float* __restrict__ dinv,
                            int* __restrict__ rowperm, int* __restrict__ sortpos,
                            int* __restrict__ chunk_off, int* __restrict__ chunk_len) {
  __shared__ int hist[64];
  __shared__ int base[64];
  int t = threadIdx.x;  // 256 threads
  if (t < 64) hist[t] = 0;
  __syncthreads();
  for (int r = t; r < NN; r += 256) {
    int d = indeg[r]; if (d > 63) d = 63;
    atomicAdd(&hist[d], 1);
    int od = outdeg[r]; if (od < 1) od = 1;
    dinv[r] = 1.0f / (float)od;
  }
  __syncthreads();
  if (t == 0) {
    int acc = 0;
    for (int i = 0; i < 64; ++i) { base[i] = acc; acc += hist[i]; }
  }
  __syncthreads();
  for (int r = t; r < NN; r += 256) {
    int d = indeg[r]; if (d > 63) d = 63;
    int pos = atomicAdd(&base[d], 1);
    rowperm[pos] = r;
    sortpos[r] = pos;
  }
  __syncthreads();
  if (t < NCHUNK) {
    int m = 0;
    for (int i = 0; i < 64; ++i) {
      int d = indeg[rowperm[(t << 6) + i]];
      if (d > m) m = d;
    }
    chunk_len[t] = (m + 1) & ~1;  // even
  }
  __syncthreads();
  if (t == 0) {
    int acc = 0;
    for (int c = 0; c < NCHUNK; ++c) { chunk_off[c] = acc; acc += chunk_len[c] << 6; }
    chunk_off[NCHUNK] = acc;
  }
}

// zero the prefetch tail of the scheduled ELL (pipeline over-reads <= 8 slabs)
__global__ void zero_tail(const int* __restrict__ chunk_off, int2* __restrict__ e2) {
  int total = chunk_off[NCHUNK];
  e2[total + threadIdx.x] = make_int2(0, 0);
}

// scatter edges into lane-major ELL (fill order): {LDS byte offset, weight bits}
__global__ void fill_ell(const int* __restrict__ senders, const int* __restrict__ receivers,
                         const int* __restrict__ sortpos, const int* __restrict__ chunk_off,
                         const float* __restrict__ dinv, int* __restrict__ fillc,
                         int2* __restrict__ ell) {
  int e = blockIdx.x * blockDim.x + threadIdx.x;
  if (e < NE) {
    int r = receivers[e], s = senders[e];
    int p = sortpos[r];
    int tslot = atomicAdd(&fillc[r], 1);
    int slot = chunk_off[p >> 6] + (tslot << 6) + (p & 63);
    ell[slot] = make_int2(xp(sortpos[s]), __float_as_int(dinv[s]));
  }
}

// Greedy bipartite edge-coloring per 8-lane track (as round 7) with slab-granular
// src prefetch so the serial bitmask work hides the L2 read latency.
__global__ void sched_ell(const int* __restrict__ chunk_off,
                          const int* __restrict__ chunk_len,
                          const int* __restrict__ rowperm,
                          const int* __restrict__ indeg,
                          const int2* __restrict__ src, int2* __restrict__ dst) {
  int tid = blockIdx.x * blockDim.x + threadIdx.x;  // <<<8,64>>> = 512 tracks
  if (tid >= NCHUNK * 8) return;
  int c = tid >> 3;
  int trk = tid & 7;
  int base = chunk_off[c];
  int len = chunk_len[c];
  int l0 = trk << 3;

  int d[8];
  u64 freeL[8];
  int dmax = 0;
#pragma unroll
  for (int j = 0; j < 8; ++j) {
    int dd = indeg[rowperm[(c << 6) + l0 + j]];
    if (dd > 63) dd = 63;
    d[j] = dd;
    if (dd > dmax) dmax = dd;
  }
  if (len > 63) {  // fallback (never hit for Poisson(8) degrees): plain copy
#pragma unroll
    for (int j = 0; j < 8; ++j) {
      for (int t = 0; t < d[j]; ++t) dst[base + (t << 6) + l0 + j] = src[base + (t << 6) + l0 + j];
      for (int t = d[j]; t < len; ++t) dst[base + (t << 6) + l0 + j] = make_int2(((t + j) & 7) << 4, 0);
    }
    return;
  }
  u64 full = (len == 0) ? 0 : ((1ull << len) - 1);
#pragma unroll
  for (int j = 0; j < 8; ++j) freeL[j] = full;
  u64 fC[8];
#pragma unroll
  for (int q = 0; q < 8; ++q) fC[q] = full;

  int2 cur[8], nxt[8];
#pragma unroll
  for (int j = 0; j < 8; ++j) cur[j] = src[base + l0 + j];  // slab 0
  for (int t = 0; t < dmax; ++t) {
#pragma unroll
    for (int j = 0; j < 8; ++j) nxt[j] = src[base + ((t + 1) << 6) + l0 + j];
#pragma unroll
    for (int j = 0; j < 8; ++j) {
      if (t < d[j]) {
        int2 e = cur[j];
        int cls = (e.x >> 4) & 7;
        u64 fc = 0;
#pragma unroll
        for (int q = 0; q < 8; ++q) fc = (q == cls) ? fC[q] : fc;
        u64 avail = freeL[j] & fc;
        u64 pool = avail ? avail : freeL[j];   // freeL[j] nonzero: d[j] <= len
        u64 pick = pool & (~pool + 1);
        int slab = __builtin_ctzll(pick);
        freeL[j] &= ~pick;
        if (avail) {
#pragma unroll
          for (int q = 0; q < 8; ++q) if (q == cls) fC[q] &= ~pick;
        }
        dst[base + (slab << 6) + l0 + j] = e;
      }
    }
#pragma unroll
    for (int j = 0; j < 8; ++j) cur[j] = nxt[j];
  }
  // padding: every leftover (lane, slab) gets a class still free at that slab
#pragma unroll
  for (int j = 0; j < 8; ++j) {
    u64 rem = freeL[j];
    while (rem) {
      u64 pick = rem & (~rem + 1);
      rem &= rem - 1;
      int slab = __builtin_ctzll(pick);
      int cls = 0;
#pragma unroll
      for (int q = 7; q >= 0; --q) if (fC[q] & pick) cls = q;
#pragma unroll
      for (int q = 0; q < 8; ++q) if (q == cls) fC[q] &= ~pick;
      dst[base + (slab << 6) + l0 + j] = make_int2(cls << 4, 0);
    }
  }
}

// ---- fused 16-step iteration: block owns cols [c0, c0+16) in LDS ----

#define MIXL(acc, srcv) \
  asm("v_fma_mix_f32 %0, %1, %2, %0 op_sel_hi:[1,0,0]" : "+v"(acc) : "v"(srcv), "v"(w))
#define MIXH(acc, srcv) \
  asm("v_fma_mix_f32 %0, %1, %2, %0 op_sel:[1,0,0] op_sel_hi:[1,0,0]" : "+v"(acc) : "v"(srcv), "v"(w))

#define MIX16(lo, hi) \
  MIXL(a[0], lo.x);  MIXH(a[1], lo.x);  \
  MIXL(a[2], lo.y);  MIXH(a[3], lo.y);  \
  MIXL(a[4], lo.z);  MIXH(a[5], lo.z);  \
  MIXL(a[6], lo.w);  MIXH(a[7], lo.w);  \
  MIXL(a[8], hi.x);  MIXH(a[9], hi.x);  \
  MIXL(a[10], hi.y); MIXH(a[11], hi.y); \
  MIXL(a[12], hi.z); MIXH(a[13], hi.z); \
  MIXL(a[14], hi.w); MIXH(a[15], hi.w)

#define LDSR(dst, addr) dst = *reinterpret_cast<const int4*>(Xb + (addr))

__global__ __launch_bounds__(THREADS, 4)
void fused_kernel(const int2* __restrict__ ell,
                  const int* __restrict__ chunk_off,
                  const int* __restrict__ chunk_len,
                  const int* __restrict__ rowperm,
                  float* __restrict__ pe) {
  __shared__ __align__(16) h_t X[NN * CW];  // 128 KiB
  char* Xb = (char*)X;
  int c0 = blockIdx.x * CW;
  int tid = threadIdx.x;
  int wave = tid >> 6, lane = tid & 63;

  // identity slice init (slot p holds row rowperm[p])
  for (int p = tid; p < NN; p += THREADS) {
    int dd = rowperm[p] - c0;
    h8 lo8, hi8;
#pragma unroll
    for (int j = 0; j < 8; ++j) {
      lo8[j] = (h_t)((dd == j) ? 1.0f : 0.0f);
      hi8[j] = (h_t)((dd == 8 + j) ? 1.0f : 0.0f);
    }
    int xb = xp(p);
    *reinterpret_cast<h8*>(Xb + xb) = lo8;
    *reinterpret_cast<h8*>(Xb + (xb ^ 16)) = hi8;
  }
  __syncthreads();

  for (int k = 0; k < PED; ++k) {
    h8 rlo[PASSES], rhi[PASSES];
#pragma unroll
    for (int pass = 0; pass < PASSES; ++pass) {
      // boustrophedon: each wave's 4 chunk ranks sum to a constant -> balanced
      int chunk = (pass << 4) + ((pass & 1) ? (15 - wave) : wave);
      int base = chunk_off[chunk];
      int len = chunk_len[chunk];           // even
      int r = rowperm[(chunk << 6) + lane];
      float a[16];
#pragma unroll
      for (int j = 0; j < 16; ++j) a[j] = 0.f;

      // depth-4 software pipeline: ELL held 8 slabs ahead, ds issued 4 ahead.
      // over-reads (<=8 slabs) land in the next chunk / zeroed tail: safe.
      const int2* ep = ell + base + lane;
      int2 e[8];
#pragma unroll
      for (int i = 0; i < 8; ++i) e[i] = ep[i << 6];
      int4 xl[4], xh[4];
#pragma unroll
      for (int i = 0; i < 4; ++i) { LDSR(xl[i], e[i].x); LDSR(xh[i], e[i].x ^ 16); }
      int t = 0;
      for (; t + 4 <= len; t += 4) {
        ep += 256;
#pragma unroll
        for (int i = 0; i < 4; ++i) {
          float w = __int_as_float(e[i].y);
          MIX16(xl[i], xh[i]);
          LDSR(xl[i], e[i + 4].x);            // ds for slab t+4+i (4 ahead)
          LDSR(xh[i], e[i + 4].x ^ 16);
          e[i] = e[i + 4];
          e[i + 4] = ep[(i + 4) << 6];        // ELL for slab t+8+i (8 ahead)
        }
      }
      if (t < len) {                          // len%4 == 2: one fixed tail pair
        float w = __int_as_float(e[0].y);
        MIX16(xl[0], xh[0]);
        w = __int_as_float(e[1].y);
        MIX16(xl[1], xh[1]);
      }

      h8 plo, phi;
#pragma unroll
      for (int j = 0; j < 8; ++j) { plo[j] = (h_t)a[j]; phi[j] = (h_t)a[8 + j]; }
      rlo[pass] = plo; rhi[pass] = phi;
      int dj = r - c0;
      if (dj >= 0 && dj < CW) {              // rare: diagonal entry, fp32 pre-rounding
        float dv = a[0];
#pragma unroll
        for (int j = 1; j < 16; ++j) dv = (dj == j) ? a[j] : dv;
        pe[r * PED + k] = dv;
      }
    }
    __syncthreads();
#pragma unroll
    for (int pass = 0; pass < PASSES; ++pass) {
      int chunk = (pass << 4) + ((pass & 1) ? (15 - wave) : wave);
      int xb = xp((chunk << 6) + lane);       // balanced write granules
      *reinterpret_cast<h8*>(Xb + xb) = rlo[pass];
      *reinterpret_cast<h8*>(Xb + (xb ^ 16)) = rhi[pass];
    }
    __syncthreads();
  }
}

// out[r,h] = sum_k pe[r,k] * W[k,h] + b[h]
__global__ void out_kernel(const float* __restrict__ pe, const float* __restrict__ W,
                           const float* __restrict__ bvec, float* __restrict__ out) {
  __shared__ float sW[PED * HID];
  int r = blockIdx.x;
  int h = threadIdx.x;
  for (int i = h; i < PED * HID; i += HID) sW[i] = W[i];
  __syncthreads();
  float acc = bvec[h];
  float p[PED];
#pragma unroll
  for (int kk = 0; kk < PED; ++kk) p[kk] = pe[r * PED + kk];
#pragma unroll
  for (int kk = 0; kk < PED; ++kk) acc = fmaf(p[kk], sW[kk * HID + h], acc);
  out[r * HID + h] = acc;
}

extern "C" void kernel_launch(void* const* d_in, const int* in_sizes, int n_in,
                              void* d_out, int out_size, void* d_ws, size_t ws_size,
                              hipStream_t stream) {
  // inputs: 0=nodes (unused), 1=senders, 2=receivers, 3=W, 4=b
  const int* senders = (const int*)d_in[1];
  const int* receivers = (const int*)d_in[2];
  const float* W = (const float*)d_in[3];
  const float* bvec = (const float*)d_in[4];
  float* out = (float*)d_out;

  char* p = (char*)d_ws;
  int* outdeg = (int*)p;    p += (size_t)NN * 4;
  int* indeg = (int*)p;     p += (size_t)NN * 4;
  int* fillc = (int*)p;     p += (size_t)NN * 4;
  float* dinv = (float*)p;  p += (size_t)NN * 4;
  int* rowperm = (int*)p;   p += (size_t)NN * 4;
  int* sortpos = (int*)p;   p += (size_t)NN * 4;
  int* chunk_off = (int*)p; p += 128 * 4;
  int* chunk_len = (int*)p; p += 128 * 4;
  float* pe = (float*)p;    p += (size_t)NN * PED * 4;
  size_t ell_slots = (size_t)64 * NE + 2048;  // worst-case padded bound + tail
  int2* ell = (int2*)p;     p += ell_slots * sizeof(int2);
  int2* ell2 = (int2*)p;

  hipMemsetAsync(d_ws, 0, (size_t)NN * 4 * 3, stream);  // outdeg/indeg/fillc
  count_kernel<<<NE / 256, 256, 0, stream>>>(senders, receivers, outdeg, indeg);
  sort_kernel<<<1, 256, 0, stream>>>(indeg, outdeg, dinv, rowperm, sortpos, chunk_off, chunk_len);
  zero_tail<<<1, 1024, 0, stream>>>(chunk_off, ell2);
  fill_ell<<<NE / 256, 256, 0, stream>>>(senders, receivers, sortpos, chunk_off, dinv, fillc, ell);
  sched_ell<<<8, 64, 0, stream>>>(chunk_off, chunk_len, rowperm, indeg, ell, ell2);

  fused_kernel<<<NN / CW, THREADS, 0, stream>>>(ell2, chunk_off, chunk_len, rowperm, pe);

  out_kernel<<<NN, HID, 0, stream>>>(pe, W, bvec, out);
}

// Round 9
// 208.087 us; speedup vs baseline: 1.1951x; 1.1951x over previous
//
#include <hip/hip_runtime.h>

#define NN 4096
#define NE 32768
#define PED 16
#define HID 128
#define CW 16          // columns per block slice
#define NCHUNK 64      // NN/64 rows per chunk
#define THREADS 1024   // 16 waves
#define PASSES 4       // NCHUNK / 16 waves

typedef _Float16 h_t;
typedef _Float16 h8 __attribute__((ext_vector_type(8)));
typedef unsigned long long u64;

// LDS BYTE offset for SORTED slot p (row rowperm[p]).
// 128-B window = 4 slots x 32 B (lo half 16 B + hi half 16 B = 16 fp16 cols).
// granule g = ((p&3)<<1) | window-parity; hi half = ^16.
__device__ __forceinline__ int xp(int p) {
  int g = ((p & 3) << 1) | ((p >> 2) & 1);
  return ((p >> 2) << 7) | (g << 4);
}

// ---- preprocessing (consolidated): counting, dinv, fillc-zero, counting-sort,
// chunk lengths/offsets — one single-block kernel, LDS histograms ----

__global__ void sort_all(const int* __restrict__ senders, const int* __restrict__ receivers,
                         float* __restrict__ dinv, int* __restrict__ indeg_g,
                         int* __restrict__ fillc,
                         int* __restrict__ rowperm, int* __restrict__ sortpos,
                         int* __restrict__ chunk_off, int* __restrict__ chunk_len) {
  __shared__ int ld_in[NN];   // 16 KB
  __shared__ int ld_out[NN];  // 16 KB
  __shared__ int hist[64];
  __shared__ int hbase[64];
  int t = threadIdx.x;  // 1024
  for (int i = t; i < NN; i += 1024) { ld_in[i] = 0; ld_out[i] = 0; }
  if (t < 64) hist[t] = 0;
  __syncthreads();
  for (int e = t; e < NE; e += 1024) {
    atomicAdd(&ld_out[senders[e]], 1);
    atomicAdd(&ld_in[receivers[e]], 1);
  }
  __syncthreads();
  for (int r = t; r < NN; r += 1024) {
    int od = ld_out[r]; if (od < 1) od = 1;
    dinv[r] = 1.0f / (float)od;
    fillc[r] = 0;
    int d = ld_in[r]; if (d > 63) d = 63;
    indeg_g[r] = d;  // clamped in-degree
    atomicAdd(&hist[d], 1);
  }
  __syncthreads();
  if (t == 0) {
    int acc = 0;
    for (int i = 0; i < 64; ++i) { hbase[i] = acc; acc += hist[i]; }
  }
  __syncthreads();
  for (int r = t; r < NN; r += 1024) {
    int d = ld_in[r]; if (d > 63) d = 63;
    int pos = atomicAdd(&hbase[d], 1);
    rowperm[pos] = r;
    sortpos[r] = pos;
  }
  __syncthreads();
  if (t < NCHUNK) {
    int m = 0;
    for (int i = 0; i < 64; ++i) {
      int rr = rowperm[(t << 6) + i];
      int d = ld_in[rr]; if (d > 63) d = 63;
      if (d > m) m = d;
    }
    chunk_len[t] = (m + 1) & ~1;  // even
  }
  __syncthreads();
  if (t == 0) {
    int acc = 0;
    for (int c = 0; c < NCHUNK; ++c) { chunk_off[c] = acc; acc += chunk_len[c] << 6; }
    chunk_off[NCHUNK] = acc;
  }
}

// scatter edges into lane-major ELL (fill order): {LDS byte offset, weight bits}
__global__ void fill_ell(const int* __restrict__ senders, const int* __restrict__ receivers,
                         const int* __restrict__ sortpos, const int* __restrict__ chunk_off,
                         const float* __restrict__ dinv, int* __restrict__ fillc,
                         int2* __restrict__ ell) {
  int e = blockIdx.x * blockDim.x + threadIdx.x;
  if (e < NE) {
    int r = receivers[e], s = senders[e];
    int p = sortpos[r];
    int tslot = atomicAdd(&fillc[r], 1);
    int slot = chunk_off[p >> 6] + (tslot << 6) + (p & 63);
    ell[slot] = make_int2(xp(sortpos[s]), __float_as_int(dinv[s]));
  }
}

// Greedy bipartite edge-coloring per 8-lane track with slab-granular src
// prefetch; also zeroes the scheduled-ELL prefetch tail.
__global__ void sched_ell(const int* __restrict__ chunk_off,
                          const int* __restrict__ chunk_len,
                          const int* __restrict__ rowperm,
                          const int* __restrict__ indeg,
                          const int2* __restrict__ src, int2* __restrict__ dst) {
  int tid = blockIdx.x * blockDim.x + threadIdx.x;  // <<<8,64>>> = 512 tracks
  if (tid >= NCHUNK * 8) return;
  {
    int total = chunk_off[NCHUNK];
    for (int i = tid; i < 2048; i += 512) dst[total + i] = make_int2(0, 0);
  }
  int c = tid >> 3;
  int trk = tid & 7;
  int base = chunk_off[c];
  int len = chunk_len[c];
  int l0 = trk << 3;

  int d[8];
  u64 freeL[8];
  int dmax = 0;
#pragma unroll
  for (int j = 0; j < 8; ++j) {
    int dd = indeg[rowperm[(c << 6) + l0 + j]];  // already clamped <= 63
    d[j] = dd;
    if (dd > dmax) dmax = dd;
  }
  if (len > 63) {  // fallback (never hit for Poisson(8) degrees): plain copy
#pragma unroll
    for (int j = 0; j < 8; ++j) {
      for (int t = 0; t < d[j]; ++t) dst[base + (t << 6) + l0 + j] = src[base + (t << 6) + l0 + j];
      for (int t = d[j]; t < len; ++t) dst[base + (t << 6) + l0 + j] = make_int2(((t + j) & 7) << 4, 0);
    }
    return;
  }
  u64 full = (len == 0) ? 0 : ((1ull << len) - 1);
#pragma unroll
  for (int j = 0; j < 8; ++j) freeL[j] = full;
  u64 fC[8];
#pragma unroll
  for (int q = 0; q < 8; ++q) fC[q] = full;

  int2 cur[8], nxt[8];
#pragma unroll
  for (int j = 0; j < 8; ++j) cur[j] = src[base + l0 + j];  // slab 0
  for (int t = 0; t < dmax; ++t) {
#pragma unroll
    for (int j = 0; j < 8; ++j) nxt[j] = src[base + ((t + 1) << 6) + l0 + j];
#pragma unroll
    for (int j = 0; j < 8; ++j) {
      if (t < d[j]) {
        int2 e = cur[j];
        int cls = (e.x >> 4) & 7;
        u64 fc = 0;
#pragma unroll
        for (int q = 0; q < 8; ++q) fc = (q == cls) ? fC[q] : fc;
        u64 avail = freeL[j] & fc;
        u64 pool = avail ? avail : freeL[j];   // freeL[j] nonzero: d[j] <= len
        u64 pick = pool & (~pool + 1);
        int slab = __builtin_ctzll(pick);
        freeL[j] &= ~pick;
        if (avail) {
#pragma unroll
          for (int q = 0; q < 8; ++q) if (q == cls) fC[q] &= ~pick;
        }
        dst[base + (slab << 6) + l0 + j] = e;
      }
    }
#pragma unroll
    for (int j = 0; j < 8; ++j) cur[j] = nxt[j];
  }
  // padding: every leftover (lane, slab) gets a class still free at that slab
#pragma unroll
  for (int j = 0; j < 8; ++j) {
    u64 rem = freeL[j];
    while (rem) {
      u64 pick = rem & (~rem + 1);
      rem &= rem - 1;
      int slab = __builtin_ctzll(pick);
      int cls = 0;
#pragma unroll
      for (int q = 7; q >= 0; --q) if (fC[q] & pick) cls = q;
#pragma unroll
      for (int q = 0; q < 8; ++q) if (q == cls) fC[q] &= ~pick;
      dst[base + (slab << 6) + l0 + j] = make_int2(cls << 4, 0);
    }
  }
}

// ---- fused 16-step iteration: block owns cols [c0, c0+16) in LDS ----

#define MIXL(acc, srcv) \
  asm("v_fma_mix_f32 %0, %1, %2, %0 op_sel_hi:[1,0,0]" : "+v"(acc) : "v"(srcv), "v"(w))
#define MIXH(acc, srcv) \
  asm("v_fma_mix_f32 %0, %1, %2, %0 op_sel:[1,0,0] op_sel_hi:[1,0,0]" : "+v"(acc) : "v"(srcv), "v"(w))

#define MIX16(lo, hi) \
  MIXL(a[0], lo.x);  MIXH(a[1], lo.x);  \
  MIXL(a[2], lo.y);  MIXH(a[3], lo.y);  \
  MIXL(a[4], lo.z);  MIXH(a[5], lo.z);  \
  MIXL(a[6], lo.w);  MIXH(a[7], lo.w);  \
  MIXL(a[8], hi.x);  MIXH(a[9], hi.x);  \
  MIXL(a[10], hi.y); MIXH(a[11], hi.y); \
  MIXL(a[12], hi.z); MIXH(a[13], hi.z); \
  MIXL(a[14], hi.w); MIXH(a[15], hi.w)

__global__ __launch_bounds__(THREADS, 4)
void fused_kernel(const int2* __restrict__ ell,
                  const int* __restrict__ chunk_off,
                  const int* __restrict__ chunk_len,
                  const int* __restrict__ rowperm,
                  float* __restrict__ pe) {
  __shared__ __align__(16) h_t X[NN * CW];  // 128 KiB
  char* Xb = (char*)X;
  int c0 = blockIdx.x * CW;
  int tid = threadIdx.x;
  int wave = tid >> 6, lane = tid & 63;

  // hoist per-pass invariants (reloaded every step otherwise: __syncthreads
  // fence semantics force the compiler to re-read globals inside the k-loop)
  int baseB[PASSES], lenB[PASSES], rB[PASSES], djB[PASSES], xbW[PASSES];
#pragma unroll
  for (int pass = 0; pass < PASSES; ++pass) {
    // boustrophedon: each wave's 4 chunk ranks sum to a constant -> balanced
    int chunk = (pass << 4) + ((pass & 1) ? (15 - wave) : wave);
    baseB[pass] = chunk_off[chunk];
    lenB[pass] = chunk_len[chunk];   // even
    int rr = rowperm[(chunk << 6) + lane];
    rB[pass] = rr;
    djB[pass] = rr - c0;
    xbW[pass] = xp((chunk << 6) + lane);
  }

  // identity slice init (slot p holds row rowperm[p])
  for (int p = tid; p < NN; p += THREADS) {
    int dd = rowperm[p] - c0;
    h8 lo8, hi8;
#pragma unroll
    for (int j = 0; j < 8; ++j) {
      lo8[j] = (h_t)((dd == j) ? 1.0f : 0.0f);
      hi8[j] = (h_t)((dd == 8 + j) ? 1.0f : 0.0f);
    }
    int xb = xp(p);
    *reinterpret_cast<h8*>(Xb + xb) = lo8;
    *reinterpret_cast<h8*>(Xb + (xb ^ 16)) = hi8;
  }
  __syncthreads();

  for (int k = 0; k < PED; ++k) {
    h8 rlo[PASSES], rhi[PASSES];
#pragma unroll
    for (int pass = 0; pass < PASSES; ++pass) {
      int base = baseB[pass];
      int len = lenB[pass];
      float a[16];
#pragma unroll
      for (int j = 0; j < 16; ++j) a[j] = 0.f;
      const int2* ep = ell + base + lane;
      int2 e0 = ep[0];   // padding/slack entries always safe to read & apply
      int2 e1 = ep[64];
      int2 e2 = ep[128];
      int2 e3 = ep[192];
      int4 lo0 = *reinterpret_cast<const int4*>(Xb + e0.x);
      int4 hi0 = *reinterpret_cast<const int4*>(Xb + (e0.x ^ 16));
      for (int t = 0; t < len; t += 2) {    // unroll-2, 4-6-slab ELL prefetch
        int2 e4 = ep[256], e5 = ep[320];
        ep += 128;
        int4 lo1 = *reinterpret_cast<const int4*>(Xb + e1.x);
        int4 hi1 = *reinterpret_cast<const int4*>(Xb + (e1.x ^ 16));
        float w = __int_as_float(e0.y);
        MIX16(lo0, hi0);
        int4 nlo = *reinterpret_cast<const int4*>(Xb + e2.x);
        int4 nhi = *reinterpret_cast<const int4*>(Xb + (e2.x ^ 16));
        w = __int_as_float(e1.y);
        MIX16(lo1, hi1);
        e0 = e2; e1 = e3; e2 = e4; e3 = e5;
        lo0 = nlo; hi0 = nhi;
      }
      h8 plo, phi;
#pragma unroll
      for (int j = 0; j < 8; ++j) { plo[j] = (h_t)a[j]; phi[j] = (h_t)a[8 + j]; }
      rlo[pass] = plo; rhi[pass] = phi;
      int dj = djB[pass];
      if (dj >= 0 && dj < CW) {            // rare: diagonal entry, fp32 pre-rounding
        float dv = a[0];
#pragma unroll
        for (int j = 1; j < 16; ++j) dv = (dj == j) ? a[j] : dv;
        pe[rB[pass] * PED + k] = dv;
      }
    }
    __syncthreads();
#pragma unroll
    for (int pass = 0; pass < PASSES; ++pass) {
      int xb = xbW[pass];                   // balanced write granules
      *reinterpret_cast<h8*>(Xb + xb) = rlo[pass];
      *reinterpret_cast<h8*>(Xb + (xb ^ 16)) = rhi[pass];
    }
    __syncthreads();
  }
}

// out[r,h] = sum_k pe[r,k] * W[k,h] + b[h]
__global__ void out_kernel(const float* __restrict__ pe, const float* __restrict__ W,
                           const float* __restrict__ bvec, float* __restrict__ out) {
  __shared__ float sW[PED * HID];
  int r = blockIdx.x;
  int h = threadIdx.x;
  for (int i = h; i < PED * HID; i += HID) sW[i] = W[i];
  __syncthreads();
  float acc = bvec[h];
  float p[PED];
#pragma unroll
  for (int kk = 0; kk < PED; ++kk) p[kk] = pe[r * PED + kk];
#pragma unroll
  for (int kk = 0; kk < PED; ++kk) acc = fmaf(p[kk], sW[kk * HID + h], acc);
  out[r * HID + h] = acc;
}

extern "C" void kernel_launch(void* const* d_in, const int* in_sizes, int n_in,
                              void* d_out, int out_size, void* d_ws, size_t ws_size,
                              hipStream_t stream) {
  // inputs: 0=nodes (unused), 1=senders, 2=receivers, 3=W, 4=b
  const int* senders = (const int*)d_in[1];
  const int* receivers = (const int*)d_in[2];
  const float* W = (const float*)d_in[3];
  const float* bvec = (const float*)d_in[4];
  float* out = (float*)d_out;

  char* p = (char*)d_ws;
  int* indeg = (int*)p;     p += (size_t)NN * 4;
  int* fillc = (int*)p;     p += (size_t)NN * 4;
  float* dinv = (float*)p;  p += (size_t)NN * 4;
  int* rowperm = (int*)p;   p += (size_t)NN * 4;
  int* sortpos = (int*)p;   p += (size_t)NN * 4;
  int* chunk_off = (int*)p; p += 128 * 4;
  int* chunk_len = (int*)p; p += 128 * 4;
  float* pe = (float*)p;    p += (size_t)NN * PED * 4;
  size_t ell_slots = (size_t)64 * NE + 2048;  // worst-case padded bound + tail
  int2* ell = (int2*)p;     p += ell_slots * sizeof(int2);
  int2* ell2 = (int2*)p;

  sort_all<<<1, 1024, 0, stream>>>(senders, receivers, dinv, indeg, fillc,
                                   rowperm, sortpos, chunk_off, chunk_len);
  fill_ell<<<NE / 256, 256, 0, stream>>>(senders, receivers, sortpos, chunk_off, dinv, fillc, ell);
  sched_ell<<<8, 64, 0, stream>>>(chunk_off, chunk_len, rowperm, indeg, ell, ell2);

  fused_kernel<<<NN / CW, THREADS, 0, stream>>>(ell2, chunk_off, chunk_len, rowperm, pe);

  out_kernel<<<NN, HID, 0, stream>>>(pe, W, bvec, out);
}

// Round 10
// 206.709 us; speedup vs baseline: 1.2030x; 1.0067x over previous
//
#include <hip/hip_runtime.h>

#define NN 4096
#define NE 32768
#define PED 16
#define HID 128
#define CW 16          // columns per block slice
#define NCHUNK 64      // NN/64 rows per chunk
#define THREADS 1024   // 16 waves
#define PASSES 4       // NCHUNK / 16 waves

typedef _Float16 h_t;
typedef _Float16 h8 __attribute__((ext_vector_type(8)));
typedef unsigned long long u64;

// LDS BYTE offset for SORTED slot p (row rowperm[p]).
// 128-B window = 4 slots x 32 B (lo half 16 B + hi half 16 B = 16 fp16 cols).
// granule g = ((p&3)<<1) | window-parity; hi half = ^16.
__device__ __forceinline__ int xp(int p) {
  int g = ((p & 3) << 1) | ((p >> 2) & 1);
  return ((p >> 2) << 7) | (g << 4);
}

// ---- preprocessing ----

// parallel edge counting (global atomics over zeroed buffers)
__global__ void count_kernel(const int* __restrict__ senders,
                             const int* __restrict__ receivers,
                             int* __restrict__ outdeg, int* __restrict__ indeg) {
  int e = blockIdx.x * blockDim.x + threadIdx.x;
  if (e < NE) {
    atomicAdd(&outdeg[senders[e]], 1);
    atomicAdd(&indeg[receivers[e]], 1);
  }
}

// single-block row-level work only: dinv, fillc-zero, clamp, counting sort,
// chunk lengths/offsets
__global__ void perm_kernel(const int* __restrict__ outdeg, int* __restrict__ indeg,
                            float* __restrict__ dinv, int* __restrict__ fillc,
                            int* __restrict__ rowperm, int* __restrict__ sortpos,
                            int* __restrict__ chunk_off, int* __restrict__ chunk_len) {
  __shared__ int ld_d[NN];  // clamped in-degrees, 16 KB
  __shared__ int hist[64];
  __shared__ int hbase[64];
  int t = threadIdx.x;  // 1024
  if (t < 64) hist[t] = 0;
  __syncthreads();
  for (int r = t; r < NN; r += 1024) {
    int od = outdeg[r]; if (od < 1) od = 1;
    dinv[r] = 1.0f / (float)od;
    fillc[r] = 0;
    int d = indeg[r]; if (d > 63) d = 63;
    ld_d[r] = d;
    indeg[r] = d;  // clamped, consumed by sched_ell
    atomicAdd(&hist[d], 1);
  }
  __syncthreads();
  if (t == 0) {
    int acc = 0;
    for (int i = 0; i < 64; ++i) { hbase[i] = acc; acc += hist[i]; }
  }
  __syncthreads();
  for (int r = t; r < NN; r += 1024) {
    int pos = atomicAdd(&hbase[ld_d[r]], 1);
    rowperm[pos] = r;
    sortpos[r] = pos;
  }
  __syncthreads();
  if (t < NCHUNK) {
    int m = 0;
    for (int i = 0; i < 64; ++i) {
      int d = ld_d[rowperm[(t << 6) + i]];
      if (d > m) m = d;
    }
    chunk_len[t] = (m + 1) & ~1;  // even
  }
  __syncthreads();
  if (t == 0) {
    int acc = 0;
    for (int c = 0; c < NCHUNK; ++c) { chunk_off[c] = acc; acc += chunk_len[c] << 6; }
    chunk_off[NCHUNK] = acc;
  }
}

// scatter edges into lane-major ELL (fill order): {LDS byte offset, weight bits}
__global__ void fill_ell(const int* __restrict__ senders, const int* __restrict__ receivers,
                         const int* __restrict__ sortpos, const int* __restrict__ chunk_off,
                         const float* __restrict__ dinv, int* __restrict__ fillc,
                         int2* __restrict__ ell) {
  int e = blockIdx.x * blockDim.x + threadIdx.x;
  if (e < NE) {
    int r = receivers[e], s = senders[e];
    int p = sortpos[r];
    int tslot = atomicAdd(&fillc[r], 1);
    int slot = chunk_off[p >> 6] + (tslot << 6) + (p & 63);
    ell[slot] = make_int2(xp(sortpos[s]), __float_as_int(dinv[s]));
  }
}

// Greedy bipartite edge-coloring per 8-lane track with slab-granular src
// prefetch; also zeroes the scheduled-ELL prefetch tail.
__global__ void sched_ell(const int* __restrict__ chunk_off,
                          const int* __restrict__ chunk_len,
                          const int* __restrict__ rowperm,
                          const int* __restrict__ indeg,
                          const int2* __restrict__ src, int2* __restrict__ dst) {
  int tid = blockIdx.x * blockDim.x + threadIdx.x;  // <<<8,64>>> = 512 tracks
  if (tid >= NCHUNK * 8) return;
  {
    int total = chunk_off[NCHUNK];
    for (int i = tid; i < 2048; i += 512) dst[total + i] = make_int2(0, 0);
  }
  int c = tid >> 3;
  int trk = tid & 7;
  int base = chunk_off[c];
  int len = chunk_len[c];
  int l0 = trk << 3;

  int d[8];
  u64 freeL[8];
  int dmax = 0;
#pragma unroll
  for (int j = 0; j < 8; ++j) {
    int dd = indeg[rowperm[(c << 6) + l0 + j]];  // already clamped <= 63
    d[j] = dd;
    if (dd > dmax) dmax = dd;
  }
  if (len > 63) {  // fallback (never hit for Poisson(8) degrees): plain copy
#pragma unroll
    for (int j = 0; j < 8; ++j) {
      for (int t = 0; t < d[j]; ++t) dst[base + (t << 6) + l0 + j] = src[base + (t << 6) + l0 + j];
      for (int t = d[j]; t < len; ++t) dst[base + (t << 6) + l0 + j] = make_int2(((t + j) & 7) << 4, 0);
    }
    return;
  }
  u64 full = (len == 0) ? 0 : ((1ull << len) - 1);
#pragma unroll
  for (int j = 0; j < 8; ++j) freeL[j] = full;
  u64 fC[8];
#pragma unroll
  for (int q = 0; q < 8; ++q) fC[q] = full;

  int2 cur[8], nxt[8];
#pragma unroll
  for (int j = 0; j < 8; ++j) cur[j] = src[base + l0 + j];  // slab 0
  for (int t = 0; t < dmax; ++t) {
#pragma unroll
    for (int j = 0; j < 8; ++j) nxt[j] = src[base + ((t + 1) << 6) + l0 + j];
#pragma unroll
    for (int j = 0; j < 8; ++j) {
      if (t < d[j]) {
        int2 e = cur[j];
        int cls = (e.x >> 4) & 7;
        u64 fc = 0;
#pragma unroll
        for (int q = 0; q < 8; ++q) fc = (q == cls) ? fC[q] : fc;
        u64 avail = freeL[j] & fc;
        u64 pool = avail ? avail : freeL[j];   // freeL[j] nonzero: d[j] <= len
        u64 pick = pool & (~pool + 1);
        int slab = __builtin_ctzll(pick);
        freeL[j] &= ~pick;
        if (avail) {
#pragma unroll
          for (int q = 0; q < 8; ++q) if (q == cls) fC[q] &= ~pick;
        }
        dst[base + (slab << 6) + l0 + j] = e;
      }
    }
#pragma unroll
    for (int j = 0; j < 8; ++j) cur[j] = nxt[j];
  }
  // padding: every leftover (lane, slab) gets a class still free at that slab
#pragma unroll
  for (int j = 0; j < 8; ++j) {
    u64 rem = freeL[j];
    while (rem) {
      u64 pick = rem & (~rem + 1);
      rem &= rem - 1;
      int slab = __builtin_ctzll(pick);
      int cls = 0;
#pragma unroll
      for (int q = 7; q >= 0; --q) if (fC[q] & pick) cls = q;
#pragma unroll
      for (int q = 0; q < 8; ++q) if (q == cls) fC[q] &= ~pick;
      dst[base + (slab << 6) + l0 + j] = make_int2(cls << 4, 0);
    }
  }
}

// ---- fused 16-step iteration + output projection epilogue ----

#define MIXL(acc, srcv) \
  asm("v_fma_mix_f32 %0, %1, %2, %0 op_sel_hi:[1,0,0]" : "+v"(acc) : "v"(srcv), "v"(w))
#define MIXH(acc, srcv) \
  asm("v_fma_mix_f32 %0, %1, %2, %0 op_sel:[1,0,0] op_sel_hi:[1,0,0]" : "+v"(acc) : "v"(srcv), "v"(w))

#define MIX16(lo, hi) \
  MIXL(a[0], lo.x);  MIXH(a[1], lo.x);  \
  MIXL(a[2], lo.y);  MIXH(a[3], lo.y);  \
  MIXL(a[4], lo.z);  MIXH(a[5], lo.z);  \
  MIXL(a[6], lo.w);  MIXH(a[7], lo.w);  \
  MIXL(a[8], hi.x);  MIXH(a[9], hi.x);  \
  MIXL(a[10], hi.y); MIXH(a[11], hi.y); \
  MIXL(a[12], hi.z); MIXH(a[13], hi.z); \
  MIXL(a[14], hi.w); MIXH(a[15], hi.w)

__global__ __launch_bounds__(THREADS, 4)
void fused_kernel(const int2* __restrict__ ell,
                  const int* __restrict__ chunk_off,
                  const int* __restrict__ chunk_len,
                  const int* __restrict__ rowperm,
                  const float* __restrict__ W,
                  const float* __restrict__ bvec,
                  float* __restrict__ out) {
  __shared__ __align__(16) h_t X[NN * CW];  // 128 KiB
  __shared__ float pe_lds[CW * PED];        // this block's 16 pe rows
  char* Xb = (char*)X;
  int c0 = blockIdx.x * CW;
  int tid = threadIdx.x;
  int wave = tid >> 6, lane = tid & 63;

  // hoist per-pass invariants (reloaded every step otherwise: __syncthreads
  // fence semantics force the compiler to re-read globals inside the k-loop)
  int baseB[PASSES], lenB[PASSES], djB[PASSES], xbW[PASSES];
#pragma unroll
  for (int pass = 0; pass < PASSES; ++pass) {
    // boustrophedon: each wave's 4 chunk ranks sum to a constant -> balanced
    int chunk = (pass << 4) + ((pass & 1) ? (15 - wave) : wave);
    baseB[pass] = chunk_off[chunk];
    lenB[pass] = chunk_len[chunk];   // even
    djB[pass] = rowperm[(chunk << 6) + lane] - c0;
    xbW[pass] = xp((chunk << 6) + lane);
  }

  // identity slice init (slot p holds row rowperm[p])
  for (int p = tid; p < NN; p += THREADS) {
    int dd = rowperm[p] - c0;
    h8 lo8, hi8;
#pragma unroll
    for (int j = 0; j < 8; ++j) {
      lo8[j] = (h_t)((dd == j) ? 1.0f : 0.0f);
      hi8[j] = (h_t)((dd == 8 + j) ? 1.0f : 0.0f);
    }
    int xb = xp(p);
    *reinterpret_cast<h8*>(Xb + xb) = lo8;
    *reinterpret_cast<h8*>(Xb + (xb ^ 16)) = hi8;
  }
  __syncthreads();

  for (int k = 0; k < PED; ++k) {
    h8 rlo[PASSES], rhi[PASSES];
#pragma unroll
    for (int pass = 0; pass < PASSES; ++pass) {
      int base = baseB[pass];
      int len = lenB[pass];
      float a[16];
#pragma unroll
      for (int j = 0; j < 16; ++j) a[j] = 0.f;
      const int2* ep = ell + base + lane;
      int2 e0 = ep[0];   // padding/slack entries always safe to read & apply
      int2 e1 = ep[64];
      int2 e2 = ep[128];
      int2 e3 = ep[192];
      int4 lo0 = *reinterpret_cast<const int4*>(Xb + e0.x);
      int4 hi0 = *reinterpret_cast<const int4*>(Xb + (e0.x ^ 16));
      for (int t = 0; t < len; t += 2) {    // unroll-2, 4-6-slab ELL prefetch
        int2 e4 = ep[256], e5 = ep[320];
        ep += 128;
        int4 lo1 = *reinterpret_cast<const int4*>(Xb + e1.x);
        int4 hi1 = *reinterpret_cast<const int4*>(Xb + (e1.x ^ 16));
        float w = __int_as_float(e0.y);
        MIX16(lo0, hi0);
        int4 nlo = *reinterpret_cast<const int4*>(Xb + e2.x);
        int4 nhi = *reinterpret_cast<const int4*>(Xb + (e2.x ^ 16));
        w = __int_as_float(e1.y);
        MIX16(lo1, hi1);
        e0 = e2; e1 = e3; e2 = e4; e3 = e5;
        lo0 = nlo; hi0 = nhi;
      }
      h8 plo, phi;
#pragma unroll
      for (int j = 0; j < 8; ++j) { plo[j] = (h_t)a[j]; phi[j] = (h_t)a[8 + j]; }
      rlo[pass] = plo; rhi[pass] = phi;
      int dj = djB[pass];
      if (dj >= 0 && dj < CW) {            // rare: diagonal entry, fp32 pre-rounding
        float dv = a[0];
#pragma unroll
        for (int j = 1; j < 16; ++j) dv = (dj == j) ? a[j] : dv;
        pe_lds[dj * PED + k] = dv;
      }
    }
    if (k != PED - 1) {                    // no write-back needed after last step
      __syncthreads();
#pragma unroll
      for (int pass = 0; pass < PASSES; ++pass) {
        int xb = xbW[pass];                 // balanced write granules
        *reinterpret_cast<h8*>(Xb + xb) = rlo[pass];
        *reinterpret_cast<h8*>(Xb + (xb ^ 16)) = rhi[pass];
      }
      __syncthreads();
    }
  }
  __syncthreads();  // pe_lds visibility

  // epilogue: out[c0+row, h] = sum_k pe_lds[row][k] * W[k][h] + b[h]
  {
    int h = tid & 127;
    int r0 = tid >> 7;   // 0..7, handles rows r0 and r0+8
    float wcol[PED];
#pragma unroll
    for (int kk = 0; kk < PED; ++kk) wcol[kk] = W[kk * HID + h];
    float bb = bvec[h];
#pragma unroll
    for (int half = 0; half < 2; ++half) {
      int row = r0 + (half << 3);
      float acc = bb;
#pragma unroll
      for (int kk = 0; kk < PED; ++kk) acc = fmaf(pe_lds[row * PED + kk], wcol[kk], acc);
      out[(size_t)(c0 + row) * HID + h] = acc;
    }
  }
}

extern "C" void kernel_launch(void* const* d_in, const int* in_sizes, int n_in,
                              void* d_out, int out_size, void* d_ws, size_t ws_size,
                              hipStream_t stream) {
  // inputs: 0=nodes (unused), 1=senders, 2=receivers, 3=W, 4=b
  const int* senders = (const int*)d_in[1];
  const int* receivers = (const int*)d_in[2];
  const float* W = (const float*)d_in[3];
  const float* bvec = (const float*)d_in[4];
  float* out = (float*)d_out;

  char* p = (char*)d_ws;
  int* outdeg = (int*)p;    p += (size_t)NN * 4;
  int* indeg = (int*)p;     p += (size_t)NN * 4;
  int* fillc = (int*)p;     p += (size_t)NN * 4;
  float* dinv = (float*)p;  p += (size_t)NN * 4;
  int* rowperm = (int*)p;   p += (size_t)NN * 4;
  int* sortpos = (int*)p;   p += (size_t)NN * 4;
  int* chunk_off = (int*)p; p += 128 * 4;
  int* chunk_len = (int*)p; p += 128 * 4;
  size_t ell_slots = (size_t)64 * NE + 2048;  // worst-case padded bound + tail
  int2* ell = (int2*)p;     p += ell_slots * sizeof(int2);
  int2* ell2 = (int2*)p;

  hipMemsetAsync(d_ws, 0, (size_t)NN * 4 * 2, stream);  // outdeg, indeg
  count_kernel<<<NE / 256, 256, 0, stream>>>(senders, receivers, outdeg, indeg);
  perm_kernel<<<1, 1024, 0, stream>>>(outdeg, indeg, dinv, fillc,
                                      rowperm, sortpos, chunk_off, chunk_len);
  fill_ell<<<NE / 256, 256, 0, stream>>>(senders, receivers, sortpos, chunk_off, dinv, fillc, ell);
  sched_ell<<<8, 64, 0, stream>>>(chunk_off, chunk_len, rowperm, indeg, ell, ell2);

  fused_kernel<<<NN / CW, THREADS, 0, stream>>>(ell2, chunk_off, chunk_len, rowperm, W, bvec, out);
}